// Round 10
// baseline (147.414 us; speedup 1.0000x reference)
//
#include <hip/hip_runtime.h>

// CharRNN GRU: B=4096, T=256, V=256, H=20, L=15, reset_after=True, drop_rate=0.
// f32 in / f32 out. ONE BATCH PER WAVE (4096 waves, 4/SIMD). ZERO LDS, zero
// barriers, zero DS ops: h(t) is broadcast through SGPRs -- pack bf16 pairs
// with DPP quad_perm + v_cvt_pk_bf16_f32, then 10x v_readlane. Lanes 0-19
// each own one hidden column's z/r/h gates: 30 v_dot2_f32_bf16 (SGPR src0).
// Activations exp2-folded (log2e pre-scaled). xW gather via global loads,
// prefetched one step ahead (vmcnt, off the lgkm-free chain).

#define BB 4096
#define TT 256
#define VV 256
#define HH 20
#define G3 60    // 3*H
#define LL 15
#define L2E 1.44269504088896340736f

static __device__ __forceinline__ unsigned short f2bf(float f) {
    union { float f; unsigned int i; } c; c.f = f;
    unsigned int x = c.i;
    return (unsigned short)((x + 0x7FFFu + ((x >> 16) & 1u)) >> 16); // RNE
}
static __device__ __forceinline__ unsigned pack2bf(float a, float b) {
    return (unsigned)f2bf(a) | ((unsigned)f2bf(b) << 16);
}
static __device__ __forceinline__ float fast_rcp(float x) {
#if __has_builtin(__builtin_amdgcn_rcpf)
    return __builtin_amdgcn_rcpf(x);
#else
    return 1.0f / x;
#endif
}
// D = a.x*b.x + a.y*b.y + c ; a is a wave-uniform SGPR (broadcast h pair)
static __device__ __forceinline__ float dot2bf_s(unsigned a, unsigned b, float c) {
    float d;
    asm("v_dot2_f32_bf16 %0, %1, %2, %3" : "=v"(d) : "s"(a), "v"(b), "v"(c));
    return d;
}
static __device__ __forceinline__ unsigned cvtpk(float lo, float hi) {
    unsigned r;
    asm("v_cvt_pk_bf16_f32 %0, %1, %2" : "=v"(r) : "v"(lo), "v"(hi));
    return r;
}
static __device__ __forceinline__ float exp2i(float x) {
    float r; asm("v_exp_f32 %0, %1" : "=v"(r) : "v"(x)); return r;
}

__global__ __launch_bounds__(64, 4) void gru_kernel(
    const int* __restrict__ x,            // [B][T] int32
    const float* __restrict__ kernelW,    // [V][3H] f32
    const float* __restrict__ rkernel,    // [H][3H] f32
    const float* __restrict__ bias,       // [2][3H] f32
    const float* __restrict__ dense_w,    // [H][L] f32
    const float* __restrict__ dense_b,    // [L] f32
    float* __restrict__ out)              // [B][L] f32
{
    const int lane = threadIdx.x;
    const int j = (lane < HH) ? lane : 0;   // idle lanes mirror column 0
    const long b = blockIdx.x;              // one batch per wave

    // U columns j, H+j, 2H+j packed bf16 (pre-scaled), 30 VGPRs, from global
    unsigned Uz[10], Ur[10], Uh[10];
    #pragma unroll
    for (int q = 0; q < 10; ++q) {
        Uz[q] = pack2bf(rkernel[(2*q)*G3 + j]        * (-L2E),
                        rkernel[(2*q+1)*G3 + j]      * (-L2E));
        Ur[q] = pack2bf(rkernel[(2*q)*G3 + HH + j]   * (-L2E),
                        rkernel[(2*q+1)*G3 + HH + j] * (-L2E));
        Uh[q] = pack2bf(rkernel[(2*q)*G3 + 2*HH + j]   * (2.0f*L2E),
                        rkernel[(2*q+1)*G3 + 2*HH + j] * (2.0f*L2E));
    }
    // z/r: input+recurrent biases additive -> one folded constant each.
    const float bzc = (bias[j]        + bias[G3 + j])      * (-L2E);
    const float brc = (bias[HH + j]   + bias[G3 + HH + j]) * (-L2E);
    const float bhi =  bias[2*HH + j]                      * (2.0f*L2E);
    const float brh =  bias[G3 + 2*HH + j]                 * (2.0f*L2E);

    const int* xrow = x + b * TT;

    // prologue: fold x-part for t=0, prefetch xv for t=1
    const int xv0 = xrow[0];
    const float* kw0 = kernelW + xv0 * G3;
    float cz = fmaf(kw0[j],        -L2E,     bzc);
    float cr = fmaf(kw0[HH + j],   -L2E,     brc);
    float ch = fmaf(kw0[2*HH + j], 2.0f*L2E, bhi);
    int xvA = xrow[1];

    float hm = 0.0f;   // h(t) for my column, f32

    for (int t = 0; t < TT; ++t) {
        // ---- prefetch (vmcnt, off-chain): kW(t+1) via xvA, xv(t+2)
        const float* kwn = kernelW + xvA * G3;
        const float lz = kwn[j];
        const float lr = kwn[HH + j];
        const float lh = kwn[2*HH + j];
        const int xvB = xrow[(t + 2 < TT) ? (t + 2) : (TT - 1)];

        // ---- broadcast h(t): DPP pair-swap + cvt_pk + 10x readlane -> SGPRs
        // quad_perm [1,0,3,2] = 0xB1: lane 2i gets h(2i+1), pairs are in-quad
        const int partner = __builtin_amdgcn_update_dpp(
            0, __float_as_int(hm), 0xB1, 0xF, 0xF, true);
        const unsigned pk = cvtpk(hm, __int_as_float(partner)); // (h2i|h2i+1) @ even lanes
        unsigned hp[10];
        #pragma unroll
        for (int q = 0; q < 10; ++q)
            hp[q] = (unsigned)__builtin_amdgcn_readlane((int)pk, 2 * q);

        // ---- two dot2 chains per gate; accumulators seeded with x-part
        float za = cz,  ra = cr,  ha = brh;
        float zb = 0.f, rb = 0.f, hb = 0.f;
        #pragma unroll
        for (int q = 0; q < 5; ++q) {
            za = dot2bf_s(hp[q], Uz[q], za);
            ra = dot2bf_s(hp[q], Ur[q], ra);
            ha = dot2bf_s(hp[q], Uh[q], ha);
        }
        #pragma unroll
        for (int q = 5; q < 10; ++q) {
            zb = dot2bf_s(hp[q], Uz[q], zb);
            rb = dot2bf_s(hp[q], Ur[q], rb);
            hb = dot2bf_s(hp[q], Uh[q], hb);
        }

        // ---- folded activations (one v_exp + one v_rcp each)
        const float z  = fast_rcp(1.0f + exp2i(za + zb));          // sigmoid
        const float r  = fast_rcp(1.0f + exp2i(ra + rb));          // sigmoid
        const float yh = fmaf(r, ha + hb, ch);                     // 2log2e-scaled
        const float hc = fmaf(-2.0f, fast_rcp(1.0f + exp2i(yh)), 1.0f); // tanh
        hm = hc + z * (hm - hc);
        // match R9 numerics: h carried as bf16 between steps (via the pack);
        // hm itself stays f32 -- rounding happens in cvtpk next iteration.

        // ---- commit prefetched folds for t+1
        cz = fmaf(lz, -L2E,     bzc);
        cr = fmaf(lr, -L2E,     brc);
        ch = fmaf(lh, 2.0f*L2E, bhi);
        xvA = xvB;
    }

    // ---- final broadcast of h(T) for the dense head
    const int partner = __builtin_amdgcn_update_dpp(
        0, __float_as_int(hm), 0xB1, 0xF, 0xF, true);
    const unsigned pk = cvtpk(hm, __int_as_float(partner));
    unsigned hf[10];
    #pragma unroll
    for (int q = 0; q < 10; ++q)
        hf[q] = (unsigned)__builtin_amdgcn_readlane((int)pk, 2 * q);

    // ---- dense head: logits[b][l] = db[l] + sum_i h[i] * W[i][l]
    if (lane < LL) {
        float acc = dense_b[lane];
        #pragma unroll
        for (int q = 0; q < 10; ++q) {
            const unsigned wp = pack2bf(dense_w[(2*q) * LL + lane],
                                        dense_w[(2*q+1) * LL + lane]);
            float d;
            asm("v_dot2_f32_bf16 %0, %1, %2, %3"
                : "=v"(d) : "s"(hf[q]), "v"(wp), "v"(acc));
            acc = d;
        }
        out[b * LL + lane] = acc;
    }
}

extern "C" void kernel_launch(void* const* d_in, const int* in_sizes, int n_in,
                              void* d_out, int out_size, void* d_ws, size_t ws_size,
                              hipStream_t stream) {
    const int* x            = (const int*)d_in[0];
    // d_in[1] = drop_rate (0.0f) -> dropout is identity; ignored.
    const float* kernelW    = (const float*)d_in[2];
    const float* rkernel    = (const float*)d_in[3];
    const float* bias       = (const float*)d_in[4];
    const float* dense_w    = (const float*)d_in[5];
    const float* dense_b    = (const float*)d_in[6];
    float* out              = (float*)d_out;

    dim3 grid(BB);      // 4096 one-wave blocks: one batch per wave, 4 waves/SIMD
    dim3 block(64);
    gru_kernel<<<grid, block, 0, stream>>>(x, kernelW, rkernel, bias,
                                           dense_w, dense_b, out);
}

// Round 11
// 92.033 us; speedup vs baseline: 1.6018x; 1.6018x over previous
//
#include <hip/hip_runtime.h>

// CharRNN GRU: B=4096, T=256, V=256, H=20, L=15, reset_after=True, drop_rate=0.
// f32 in / f32 out. 3 batches per wave (20 lanes each), 1366 one-wave blocks.
// ZERO LDS, zero barriers, zero LDS-memory ops. h(t) exchange = DPP pair-pack
// (v_cvt_pk_bf16_f32) + 10x ds_bpermute_b32 in a SINGLE asm block with ONE
// s_waitcnt lgkmcnt(0) (crossbar-only; R8's regression was per-intrinsic lgkm
// waits, fixed by batching). U packed bf16 in 30 VGPRs, dots v_dot2_f32_bf16,
// activations exp2-folded, xW gather from global with 2-step prefetch (vmcnt).

#define BB 4096
#define TT 256
#define VV 256
#define HH 20
#define G3 60    // 3*H
#define LL 15
#define L2E 1.44269504088896340736f

static __device__ __forceinline__ unsigned short f2bf(float f) {
    union { float f; unsigned int i; } c; c.f = f;
    unsigned int x = c.i;
    return (unsigned short)((x + 0x7FFFu + ((x >> 16) & 1u)) >> 16); // RNE
}
static __device__ __forceinline__ unsigned pack2bf(float a, float b) {
    return (unsigned)f2bf(a) | ((unsigned)f2bf(b) << 16);
}
static __device__ __forceinline__ float fast_rcp(float x) {
#if __has_builtin(__builtin_amdgcn_rcpf)
    return __builtin_amdgcn_rcpf(x);
#else
    return 1.0f / x;
#endif
}
// D = a.x*b.x + a.y*b.y + c  (bf16 pairs packed in u32, f32 accumulate)
static __device__ __forceinline__ float dot2bf(unsigned a, unsigned b, float c) {
    float d;
    asm("v_dot2_f32_bf16 %0, %1, %2, %3" : "=v"(d) : "v"(a), "v"(b), "v"(c));
    return d;
}
static __device__ __forceinline__ unsigned cvtpk(float lo, float hi) {
    unsigned r;
    asm("v_cvt_pk_bf16_f32 %0, %1, %2" : "=v"(r) : "v"(lo), "v"(hi));
    return r;
}
static __device__ __forceinline__ float exp2i(float x) {
    float r; asm("v_exp_f32 %0, %1" : "=v"(r) : "v"(x)); return r;
}

// h exchange, crossbar only: pull the packed bf16 pair (h2q|h2q+1) of my
// group from even lanes. ONE asm block -> ONE lgkmcnt(0), ops pipeline.
static __device__ __forceinline__ void bperm_x10(
    unsigned pk, const int* __restrict__ ba, unsigned* __restrict__ hp) {
    asm volatile(
        "ds_bpermute_b32 %0, %10, %20\n\t"
        "ds_bpermute_b32 %1, %11, %20\n\t"
        "ds_bpermute_b32 %2, %12, %20\n\t"
        "ds_bpermute_b32 %3, %13, %20\n\t"
        "ds_bpermute_b32 %4, %14, %20\n\t"
        "ds_bpermute_b32 %5, %15, %20\n\t"
        "ds_bpermute_b32 %6, %16, %20\n\t"
        "ds_bpermute_b32 %7, %17, %20\n\t"
        "ds_bpermute_b32 %8, %18, %20\n\t"
        "ds_bpermute_b32 %9, %19, %20\n\t"
        "s_waitcnt lgkmcnt(0)"
        : "=&v"(hp[0]), "=&v"(hp[1]), "=&v"(hp[2]), "=&v"(hp[3]), "=&v"(hp[4]),
          "=&v"(hp[5]), "=&v"(hp[6]), "=&v"(hp[7]), "=&v"(hp[8]), "=&v"(hp[9])
        : "v"(ba[0]), "v"(ba[1]), "v"(ba[2]), "v"(ba[3]), "v"(ba[4]),
          "v"(ba[5]), "v"(ba[6]), "v"(ba[7]), "v"(ba[8]), "v"(ba[9]),
          "v"(pk));
}

__global__ __launch_bounds__(64, 4) void gru_kernel(
    const int* __restrict__ x,            // [B][T] int32
    const float* __restrict__ kernelW,    // [V][3H] f32
    const float* __restrict__ rkernel,    // [H][3H] f32
    const float* __restrict__ bias,       // [2][3H] f32
    const float* __restrict__ dense_w,    // [H][L] f32
    const float* __restrict__ dense_b,    // [L] f32
    float* __restrict__ out)              // [B][L] f32
{
    const int lane = threadIdx.x;          // one wave per block
    const int g3a  = lane / 20;            // 0,1,2 active; 3 for lanes 60-63
    const int g3   = (lane < 60) ? g3a : 0;
    const int j    = lane - g3a * 20;      // 0..19 (idle lanes: 0..3)
    const bool active = (lane < 60);
    const long b  = (long)blockIdx.x * 3 + g3;
    const long bc = (b < BB) ? b : (BB - 1);   // clamped for loads

    // bpermute byte addresses of my group's even lanes (per-lane constants)
    int ba[10];
    #pragma unroll
    for (int q = 0; q < 10; ++q) ba[q] = (g3 * 20 + 2 * q) * 4;

    // U columns j, H+j, 2H+j packed bf16 (pre-scaled), 30 VGPRs, from global
    unsigned Uz[10], Ur[10], Uh[10];
    #pragma unroll
    for (int q = 0; q < 10; ++q) {
        Uz[q] = pack2bf(rkernel[(2*q)*G3 + j]        * (-L2E),
                        rkernel[(2*q+1)*G3 + j]      * (-L2E));
        Ur[q] = pack2bf(rkernel[(2*q)*G3 + HH + j]   * (-L2E),
                        rkernel[(2*q+1)*G3 + HH + j] * (-L2E));
        Uh[q] = pack2bf(rkernel[(2*q)*G3 + 2*HH + j]   * (2.0f*L2E),
                        rkernel[(2*q+1)*G3 + 2*HH + j] * (2.0f*L2E));
    }
    // z/r: input+recurrent biases additive -> one folded constant each.
    const float bzc = (bias[j]        + bias[G3 + j])      * (-L2E);
    const float brc = (bias[HH + j]   + bias[G3 + HH + j]) * (-L2E);
    const float bhi =  bias[2*HH + j]                      * (2.0f*L2E);
    const float brh =  bias[G3 + 2*HH + j]                 * (2.0f*L2E);

    const int* xrow = x + bc * TT;

    // prologue: fold x-part for t=0, prefetch xv for t=1
    const int xv0 = xrow[0];
    const float* kw0 = kernelW + xv0 * G3;
    float cz = fmaf(kw0[j],        -L2E,     bzc);
    float cr = fmaf(kw0[HH + j],   -L2E,     brc);
    float ch = fmaf(kw0[2*HH + j], 2.0f*L2E, bhi);
    int xvA = xrow[1];

    float hm = 0.0f;       // h(t) for my column, f32
    unsigned pk = 0;       // packed (h2k|h2k+1) on even lanes

    for (int t = 0; t < TT; ++t) {
        // ---- prefetch (vmcnt, off-chain): kW(t+1) via xvA, xv(t+2)
        const float* kwn = kernelW + xvA * G3;
        const float lz = kwn[j];
        const float lr = kwn[HH + j];
        const float lh = kwn[2*HH + j];
        const int xvB = xrow[(t + 2 < TT) ? (t + 2) : (TT - 1)];

        // ---- exchange h(t): 10 batched bpermutes, one lgkm wait
        unsigned hp[10];
        bperm_x10(pk, ba, hp);

        // ---- two dot2 chains per gate; accumulators seeded with x-part
        float za = cz,  ra = cr,  ha = brh;
        float zb = 0.f, rb = 0.f, hb = 0.f;
        #pragma unroll
        for (int q = 0; q < 5; ++q) {
            za = dot2bf(hp[q], Uz[q], za);
            ra = dot2bf(hp[q], Ur[q], ra);
            ha = dot2bf(hp[q], Uh[q], ha);
        }
        #pragma unroll
        for (int q = 5; q < 10; ++q) {
            zb = dot2bf(hp[q], Uz[q], zb);
            rb = dot2bf(hp[q], Ur[q], rb);
            hb = dot2bf(hp[q], Uh[q], hb);
        }

        // ---- folded activations (one v_exp + one v_rcp each)
        const float z  = fast_rcp(1.0f + exp2i(za + zb));          // sigmoid
        const float r  = fast_rcp(1.0f + exp2i(ra + rb));          // sigmoid
        const float yh = fmaf(r, ha + hb, ch);                     // 2log2e-scaled
        const float hc = fmaf(-2.0f, fast_rcp(1.0f + exp2i(yh)), 1.0f); // tanh
        hm = hc + z * (hm - hc);

        // ---- pack for next exchange: DPP quad-partner swap + cvt_pk
        const int partner = __builtin_amdgcn_update_dpp(
            0, __float_as_int(hm), 0xB1, 0xF, 0xF, true);
        pk = cvtpk(hm, __int_as_float(partner));   // even lanes: (h2k|h2k+1)

        // ---- commit prefetched folds for t+1
        cz = fmaf(lz, -L2E,     bzc);
        cr = fmaf(lr, -L2E,     brc);
        ch = fmaf(lh, 2.0f*L2E, bhi);
        xvA = xvB;
    }

    // ---- final exchange of h(T) for the dense head
    unsigned fp[10];
    bperm_x10(pk, ba, fp);
    float hf[HH];
    #pragma unroll
    for (int q = 0; q < 10; ++q) {
        hf[2*q]   = __uint_as_float(fp[q] << 16);
        hf[2*q+1] = __uint_as_float(fp[q] & 0xffff0000u);
    }

    // ---- dense head: logits[b][l] = db[l] + sum_i h[i] * W[i][l]
    if (active && j < LL && b < BB) {
        float acc = dense_b[j];
        #pragma unroll
        for (int i = 0; i < HH; ++i)
            acc = fmaf(hf[i], dense_w[i * LL + j], acc);
        out[b * LL + j] = acc;
    }
}

extern "C" void kernel_launch(void* const* d_in, const int* in_sizes, int n_in,
                              void* d_out, int out_size, void* d_ws, size_t ws_size,
                              hipStream_t stream) {
    const int* x            = (const int*)d_in[0];
    // d_in[1] = drop_rate (0.0f) -> dropout is identity; ignored.
    const float* kernelW    = (const float*)d_in[2];
    const float* rkernel    = (const float*)d_in[3];
    const float* bias       = (const float*)d_in[4];
    const float* dense_w    = (const float*)d_in[5];
    const float* dense_b    = (const float*)d_in[6];
    float* out              = (float*)d_out;

    dim3 grid((BB + 2) / 3);   // 1366 one-wave blocks, 3 batches each
    dim3 block(64);
    gru_kernel<<<grid, block, 0, stream>>>(x, kernelW, rkernel, bias,
                                           dense_w, dense_b, out);
}

// Round 13
// 76.727 us; speedup vs baseline: 1.9213x; 1.1995x over previous
//
#include <hip/hip_runtime.h>

// CharRNN GRU: B=4096, T=256, V=256, H=20, L=15, reset_after=True, drop_rate=0.
// f32 in / f32 out. 3 batches per wave (20 lanes each), 1366 one-wave blocks.
// R9 numerics exactly; exchange SOFTWARE-PIPELINED across the loop backedge:
//   bottom of iter t: ds_write_b16 h(t+1) + 3 ds_reads issued (no wait)
//   top of iter t+1:  s_waitcnt lgkmcnt(2) -> pairs 0-3 usable -> start dots
//                     s_waitcnt lgkmcnt(0) -> pairs 4-9
// Waits tie the destination regs ("+v") so consumers can't hoist (rule 18),
// plus sched_barrier(0). No other lgkm ops in the loop (prefetch is global/
// vmcnt). U packed bf16 in 30 VGPRs, dots v_dot2_f32_bf16, activations
// exp2-folded (log2e pre-scaled), 2-step global prefetch of the xW gather.

#define BB 4096
#define TT 256
#define VV 256
#define HH 20
#define G3 60    // 3*H
#define LL 15
#define L2E 1.44269504088896340736f

typedef int v4i __attribute__((ext_vector_type(4)));
typedef int v2i __attribute__((ext_vector_type(2)));

static __device__ __forceinline__ unsigned short f2bf(float f) {
    union { float f; unsigned int i; } c; c.f = f;
    unsigned int x = c.i;
    return (unsigned short)((x + 0x7FFFu + ((x >> 16) & 1u)) >> 16); // RNE
}
static __device__ __forceinline__ unsigned pack2bf(float a, float b) {
    return (unsigned)f2bf(a) | ((unsigned)f2bf(b) << 16);
}
static __device__ __forceinline__ float fast_rcp(float x) {
#if __has_builtin(__builtin_amdgcn_rcpf)
    return __builtin_amdgcn_rcpf(x);
#else
    return 1.0f / x;
#endif
}
// D = a.x*b.x + a.y*b.y + c  (bf16 pairs packed in u32, f32 accumulate)
static __device__ __forceinline__ float dot2bf(unsigned a, unsigned b, float c) {
    float d;
    asm("v_dot2_f32_bf16 %0, %1, %2, %3" : "=v"(d) : "v"(a), "v"(b), "v"(c));
    return d;
}
static __device__ __forceinline__ unsigned cvtpk(float lo, float hi) {
    unsigned r;
    asm("v_cvt_pk_bf16_f32 %0, %1, %2" : "=v"(r) : "v"(lo), "v"(hi));
    return r;
}
static __device__ __forceinline__ float exp2i(float x) {
    float r; asm("v_exp_f32 %0, %1" : "=v"(r) : "v"(x)); return r;
}

// issue exchange for the NEXT step: write my bf16 h, queue the 3 reads.
// NO wait here -- the RT hides under loop glue + next iteration's prefetch.
static __device__ __forceinline__ void exch_issue(unsigned waddr, unsigned hbf,
                                                  unsigned raddr,
                                                  v4i& p0, v4i& p1, v2i& p2) {
    asm volatile(
        "ds_write_b16 %3, %4\n\t"
        "ds_read_b128 %0, %5\n\t"
        "ds_read_b128 %1, %5 offset:16\n\t"
        "ds_read_b64 %2, %5 offset:32"
        : "=&v"(p0), "=&v"(p1), "=&v"(p2)
        : "v"(waddr), "v"(hbf), "v"(raddr));
}
// counted waits; tie the registers so dependent dots can't be hoisted above.
static __device__ __forceinline__ void exch_wait_first(v4i& p0) {
    asm volatile("s_waitcnt lgkmcnt(2)" : "+v"(p0));   // write+read0 retired
    __builtin_amdgcn_sched_barrier(0);
}
static __device__ __forceinline__ void exch_wait_rest(v4i& p1, v2i& p2) {
    asm volatile("s_waitcnt lgkmcnt(0)" : "+v"(p1), "+v"(p2));
    __builtin_amdgcn_sched_barrier(0);
}

__global__ __launch_bounds__(64, 2) void gru_kernel(
    const int* __restrict__ x,            // [B][T] int32
    const float* __restrict__ kernelW,    // [V][3H] f32
    const float* __restrict__ rkernel,    // [H][3H] f32
    const float* __restrict__ bias,       // [2][3H] f32
    const float* __restrict__ dense_w,    // [H][L] f32
    const float* __restrict__ dense_b,    // [L] f32
    float* __restrict__ out)              // [B][L] f32
{
    // 3 groups * 48 B (20 bf16 + pad) + idle-lane scratch = 160 B total LDS
    __shared__ __align__(16) unsigned short hbuf[80];

    const int lane = threadIdx.x;          // one wave per block
    const int g3a  = lane / 20;            // 0,1,2 active; 3 for lanes 60-63
    const int g3   = (lane < 60) ? g3a : 0;
    const int j    = lane - g3a * 20;      // 0..19 (idle lanes: 0..3)
    const bool active = (lane < 60);
    const long b  = (long)blockIdx.x * 3 + g3;
    const long bc = (b < BB) ? b : (BB - 1);   // clamped for loads

    const unsigned hbase = (unsigned)(size_t)&hbuf[0];
    const unsigned waddr = active ? (hbase + 48u * (unsigned)g3a + 2u * (unsigned)j)
                                  : (hbase + 144u + 2u * (unsigned)(lane - 60));
    const unsigned raddr = hbase + 48u * (unsigned)g3;

    // U columns j, H+j, 2H+j packed bf16 (pre-scaled), 30 VGPRs, from global
    unsigned Uz[10], Ur[10], Uh[10];
    #pragma unroll
    for (int q = 0; q < 10; ++q) {
        Uz[q] = pack2bf(rkernel[(2*q)*G3 + j]        * (-L2E),
                        rkernel[(2*q+1)*G3 + j]      * (-L2E));
        Ur[q] = pack2bf(rkernel[(2*q)*G3 + HH + j]   * (-L2E),
                        rkernel[(2*q+1)*G3 + HH + j] * (-L2E));
        Uh[q] = pack2bf(rkernel[(2*q)*G3 + 2*HH + j]   * (2.0f*L2E),
                        rkernel[(2*q+1)*G3 + 2*HH + j] * (2.0f*L2E));
    }
    // z/r: input+recurrent biases additive -> one folded constant each.
    const float bzc = (bias[j]        + bias[G3 + j])      * (-L2E);
    const float brc = (bias[HH + j]   + bias[G3 + HH + j]) * (-L2E);
    const float bhi =  bias[2*HH + j]                      * (2.0f*L2E);
    const float brh =  bias[G3 + 2*HH + j]                 * (2.0f*L2E);

    const int* xrow = x + bc * TT;

    // prologue: fold x-part for t=0, prefetch xv for t=1
    const int xv0 = xrow[0];
    const float* kw0 = kernelW + xv0 * G3;
    float cz = fmaf(kw0[j],        -L2E,     bzc);
    float cr = fmaf(kw0[HH + j],   -L2E,     brc);
    float ch = fmaf(kw0[2*HH + j], 2.0f*L2E, bhi);
    int xvA = xrow[1];

    float hm = 0.0f;
    v4i p0, p1; v2i p2;
    exch_issue(waddr, 0u, raddr, p0, p1, p2);   // transport h(0)=0

    for (int t = 0; t < TT; ++t) {
        // ---- prefetch (vmcnt, off-chain): kW(t+1) via xvA, xv(t+2)
        const float* kwn = kernelW + xvA * G3;
        const float lz = kwn[j];
        const float lr = kwn[HH + j];
        const float lh = kwn[2*HH + j];
        const int xvB = xrow[(t + 2 < TT) ? (t + 2) : (TT - 1)];

        // ---- pairs 0-3 ready (write+read0 retired): start the dot chains
        exch_wait_first(p0);
        float za = cz,  ra = cr,  ha = brh;
        {
            const unsigned h0 = (unsigned)p0.x, h1 = (unsigned)p0.y,
                           h2 = (unsigned)p0.z, h3 = (unsigned)p0.w;
            za = dot2bf(h0, Uz[0], za); ra = dot2bf(h0, Ur[0], ra); ha = dot2bf(h0, Uh[0], ha);
            za = dot2bf(h1, Uz[1], za); ra = dot2bf(h1, Ur[1], ra); ha = dot2bf(h1, Uh[1], ha);
            za = dot2bf(h2, Uz[2], za); ra = dot2bf(h2, Ur[2], ra); ha = dot2bf(h2, Uh[2], ha);
            za = dot2bf(h3, Uz[3], za); ra = dot2bf(h3, Ur[3], ra); ha = dot2bf(h3, Uh[3], ha);
        }
        // ---- pairs 4-9
        exch_wait_rest(p1, p2);
        const unsigned h4 = (unsigned)p1.x, h5 = (unsigned)p1.y,
                       h6 = (unsigned)p1.z, h7 = (unsigned)p1.w,
                       h8 = (unsigned)p2.x, h9 = (unsigned)p2.y;
        za = dot2bf(h4, Uz[4], za); ra = dot2bf(h4, Ur[4], ra); ha = dot2bf(h4, Uh[4], ha);
        float zb = 0.f, rb = 0.f, hb = 0.f;
        zb = dot2bf(h5, Uz[5], zb); rb = dot2bf(h5, Ur[5], rb); hb = dot2bf(h5, Uh[5], hb);
        zb = dot2bf(h6, Uz[6], zb); rb = dot2bf(h6, Ur[6], rb); hb = dot2bf(h6, Uh[6], hb);
        zb = dot2bf(h7, Uz[7], zb); rb = dot2bf(h7, Ur[7], rb); hb = dot2bf(h7, Uh[7], hb);
        zb = dot2bf(h8, Uz[8], zb); rb = dot2bf(h8, Ur[8], rb); hb = dot2bf(h8, Uh[8], hb);
        zb = dot2bf(h9, Uz[9], zb); rb = dot2bf(h9, Ur[9], rb); hb = dot2bf(h9, Uh[9], hb);

        // ---- folded activations (one v_exp + one v_rcp each)
        const float r  = fast_rcp(1.0f + exp2i(ra + rb));          // sigmoid
        const float z  = fast_rcp(1.0f + exp2i(za + zb));          // sigmoid
        const float yh = fmaf(r, ha + hb, ch);                     // 2log2e-scaled
        const float hc = fmaf(-2.0f, fast_rcp(1.0f + exp2i(yh)), 1.0f); // tanh
        hm = hc + z * (hm - hc);

        // ---- pack and ISSUE next step's exchange (RT hides under glue)
        const unsigned hbf = cvtpk(hm, hm);
        exch_issue(waddr, hbf, raddr, p0, p1, p2);

        // ---- commit prefetched folds for t+1
        cz = fmaf(lz, -L2E,     bzc);
        cr = fmaf(lr, -L2E,     brc);
        ch = fmaf(lh, 2.0f*L2E, bhi);
        xvA = xvB;
    }

    // ---- final exchange (issued at t=255 bottom) carries h(256)
    asm volatile("s_waitcnt lgkmcnt(0)" : "+v"(p0), "+v"(p1), "+v"(p2));
    __builtin_amdgcn_sched_barrier(0);
    const unsigned fp[10] = { (unsigned)p0.x, (unsigned)p0.y, (unsigned)p0.z,
                              (unsigned)p0.w, (unsigned)p1.x, (unsigned)p1.y,
                              (unsigned)p1.z, (unsigned)p1.w, (unsigned)p2.x,
                              (unsigned)p2.y };
    float hf[HH];
    #pragma unroll
    for (int q = 0; q < 10; ++q) {
        hf[2*q]   = __uint_as_float(fp[q] << 16);
        hf[2*q+1] = __uint_as_float(fp[q] & 0xffff0000u);
    }

    // ---- dense head: logits[b][l] = db[l] + sum_i h[i] * W[i][l]
    if (active && j < LL && b < BB) {
        float acc = dense_b[j];
        #pragma unroll
        for (int i = 0; i < HH; ++i)
            acc = fmaf(hf[i], dense_w[i * LL + j], acc);
        out[b * LL + j] = acc;
    }
}

extern "C" void kernel_launch(void* const* d_in, const int* in_sizes, int n_in,
                              void* d_out, int out_size, void* d_ws, size_t ws_size,
                              hipStream_t stream) {
    const int* x            = (const int*)d_in[0];
    // d_in[1] = drop_rate (0.0f) -> dropout is identity; ignored.
    const float* kernelW    = (const float*)d_in[2];
    const float* rkernel    = (const float*)d_in[3];
    const float* bias       = (const float*)d_in[4];
    const float* dense_w    = (const float*)d_in[5];
    const float* dense_b    = (const float*)d_in[6];
    float* out              = (float*)d_out;

    dim3 grid((BB + 2) / 3);   // 1366 one-wave blocks, 3 batches each
    dim3 block(64);
    gru_kernel<<<grid, block, 0, stream>>>(x, kernelW, rkernel, bias,
                                           dense_w, dense_b, out);
}